// Round 5
// baseline (1644.498 us; speedup 1.0000x reference)
//
#include <hip/hip_runtime.h>
#include <hip/hip_fp16.h>

#define LDIM 512
#define BDIM 16

// ws layout: small arrays first so the fallback path works with small ws.
#define WS_A    0u          // 262144 B  (float A[256*256], A[x*256+q])
#define WS_CE   262144u     // 1024 B
#define WS_LOM  263168u     // 1024 B
#define WS_LAL  264192u     // 1024 B
#define WS_PS   265216u     // 64 B
#define WS_W    270336u     // 33554432 B (fp16 W), 16B aligned
#define WS_FAST_BYTES (270336ull + 33554432ull)

__device__ __forceinline__ float wred_add(float v) {
    #pragma unroll
    for (int off = 32; off; off >>= 1) v += __shfl_xor(v, off);
    return v;
}
__device__ __forceinline__ float wred_max(float v) {
    #pragma unroll
    for (int off = 32; off; off >>= 1) v = fmaxf(v, __shfl_xor(v, off));
    return v;
}

// Michelot exact sparsemax over a wave's 256 values (4 per lane).
// Returns c = <z,p*> - 0.5||p*||^2 + 0.5 (wave-uniform).
__device__ float sparsemax_c4(float z0, float z1, float z2, float z3) {
    float ssum = wred_add(z0 + z1 + z2 + z3);
    float tau = (ssum - 1.0f) * (1.0f / 256.0f);
    int kprev = 256;
    for (int it = 0; it < 64; ++it) {
        float s = 0.f, cnt = 0.f;
        if (z0 > tau) { s += z0; cnt += 1.f; }
        if (z1 > tau) { s += z1; cnt += 1.f; }
        if (z2 > tau) { s += z2; cnt += 1.f; }
        if (z3 > tau) { s += z3; cnt += 1.f; }
        s = wred_add(s);
        cnt = wred_add(cnt);
        tau = (s - 1.0f) / cnt;            // cnt >= 1 invariant (max > tau)
        int k = (int)cnt;
        if (k == kprev) break;
        kprev = k;
    }
    float cs = 0.f, t2 = tau * tau;
    if (z0 > tau) cs += z0 * z0 - t2;
    if (z1 > tau) cs += z1 * z1 - t2;
    if (z2 > tau) cs += z2 * z2 - t2;
    if (z3 > tau) cs += z3 * z3 - t2;
    cs = wred_add(cs);
    return 0.5f * cs + 0.5f;
}

// Rows of E (256) + omega (1) + alpha (1). All float32.
__global__ __launch_bounds__(256) void k_erow(const float* E, const float* omega,
                                              const float* alpha,
                                              float* cE, float* LOm, float* LAl) {
    int wid = blockIdx.x * 4 + (threadIdx.x >> 6);
    if (wid >= 258) return;
    int lane = threadIdx.x & 63;
    const float* row = (wid < 256) ? (E + wid * 256)
                      : (wid == 256 ? omega : alpha);
    float4 z = *(const float4*)(row + lane * 4);
    float c = sparsemax_c4(z.x, z.y, z.z, z.w);
    if (wid < 256) {
        if (lane == 0) cE[wid] = c;
    } else {
        float* dst = (wid == 256) ? LOm : LAl;
        *(float4*)(dst + lane * 4) = make_float4(c - z.x, c - z.y, c - z.z, c - z.w);
    }
}

// wid = x*256+q (4 waves of a block = consecutive q, same x -> coalesced W scatter).
// A[x*256+q] = c_T(T[q,x,:]); W3[((x*32+i)*256+q)*8+k] = fp16(exp(-T[q,x,8i+k])).
__global__ __launch_bounds__(256) void k_trow(const float* T, __half* W,
                                              float* A, int writeW) {
    int wid = blockIdx.x * 4 + (threadIdx.x >> 6);
    int lane = threadIdx.x & 63;
    int x = wid >> 8, q = wid & 255;
    const float* row = T + ((size_t)((q << 8) | x) << 8);
    float4 z = *(const float4*)(row + lane * 4);
    float c = sparsemax_c4(z.x, z.y, z.z, z.w);
    if (writeW) {
        union { uint2 v; __half h[4]; } wout;
        wout.h[0] = __float2half(__expf(-z.x));
        wout.h[1] = __float2half(__expf(-z.y));
        wout.h[2] = __float2half(__expf(-z.z));
        wout.h[3] = __float2half(__expf(-z.w));
        // lane covers n = lane*4 .. lane*4+3 -> chunk i = lane>>1, k0 = (lane&1)*4
        size_t idx = ((((size_t)x * 32 + (lane >> 1)) * 256 + q) * 8) + (size_t)((lane & 1) * 4);
        *(uint2*)(W + idx) = wout.v;
    }
    if (lane == 0) A[wid] = c;
}

// A[x,q] += cE[q] - E[q,x]
__global__ __launch_bounds__(256) void k_afix(const float* E, const float* cE, float* A) {
    int x = blockIdx.x, q = threadIdx.x;
    A[(x << 8) + q] += cE[q] - E[q * 256 + x];
}

// ---- main recursion, fast path: precomputed fp16 W table ----
__global__ __launch_bounds__(256) void k_main_fast(const int* xs, const __half* W,
                                                   const float* A, const float* LOm,
                                                   const float* LAl, float* per_seq) {
    int b = blockIdx.x, q = threadIdx.x;
    __shared__ int xsh[LDIM];
    __shared__ float red[4];
    __shared__ __align__(16) float u_f[256];
    for (int i = q; i < LDIM; i += 256) xsh[i] = xs[b * LDIM + i];
    float c = LOm[q];
    __syncthreads();

    for (int t = LDIM - 1; t >= 0; --t) {
        int x = xsh[t];
        if (x != 0) {                              // block-uniform branch
            float m = wred_max(c);
            if ((q & 63) == 0) red[q >> 6] = m;
            __syncthreads();                       // S1
            m = fmaxf(fmaxf(red[0], red[1]), fmaxf(red[2], red[3]));
            u_f[q] = __expf(c - m);
            __syncthreads();                       // S2
            const __half* Wp = W + (((size_t)x) << 16) + ((size_t)q << 3);
            float acc = 0.f;
            #pragma unroll 8
            for (int i = 0; i < 32; ++i) {
                union { uint4 v; __half h[8]; } wv;
                wv.v = *(const uint4*)(Wp + ((size_t)i << 11));
                float4 ua = *(const float4*)(u_f + (i << 3));
                float4 ub = *(const float4*)(u_f + (i << 3) + 4);
                acc = fmaf(__half2float(wv.h[0]), ua.x, acc);
                acc = fmaf(__half2float(wv.h[1]), ua.y, acc);
                acc = fmaf(__half2float(wv.h[2]), ua.z, acc);
                acc = fmaf(__half2float(wv.h[3]), ua.w, acc);
                acc = fmaf(__half2float(wv.h[4]), ub.x, acc);
                acc = fmaf(__half2float(wv.h[5]), ub.y, acc);
                acc = fmaf(__half2float(wv.h[6]), ub.z, acc);
                acc = fmaf(__half2float(wv.h[7]), ub.w, acc);
            }
            acc = fmaxf(acc, 1e-30f);              // firewall
            c = A[(x << 8) + q] + m + __logf(acc);
        }
    }

    float v = LAl[q] + c;
    float m2 = wred_max(v);
    if ((q & 63) == 0) red[q >> 6] = m2;
    __syncthreads();
    m2 = fmaxf(fmaxf(red[0], red[1]), fmaxf(red[2], red[3]));
    float es = wred_add(__expf(v - m2));
    __syncthreads();
    if ((q & 63) == 0) red[q >> 6] = es;
    __syncthreads();
    if (q == 0) per_seq[b] = m2 + __logf(red[0] + red[1] + red[2] + red[3]);
}

// ---- fallback: read T (f32) directly, exp on the fly ----
__global__ __launch_bounds__(256) void k_main_med(const int* xs, const float* T,
                                                  const float* A, const float* LOm,
                                                  const float* LAl, float* per_seq) {
    int b = blockIdx.x, q = threadIdx.x;
    __shared__ int xsh[LDIM];
    __shared__ float red[4];
    __shared__ __align__(16) float u_f[256];
    for (int i = q; i < LDIM; i += 256) xsh[i] = xs[b * LDIM + i];
    float c = LOm[q];
    __syncthreads();

    for (int t = LDIM - 1; t >= 0; --t) {
        int x = xsh[t];
        if (x != 0) {
            float m = wred_max(c);
            if ((q & 63) == 0) red[q >> 6] = m;
            __syncthreads();                       // S1
            m = fmaxf(fmaxf(red[0], red[1]), fmaxf(red[2], red[3]));
            u_f[q] = __expf(c - m);
            __syncthreads();                       // S2
            const float* Tp = T + (((size_t)(q << 8) + (size_t)x) << 8);
            float acc = 0.f;
            #pragma unroll 4
            for (int i = 0; i < 32; ++i) {
                float4 ta = *(const float4*)(Tp + (i << 3));
                float4 tb = *(const float4*)(Tp + (i << 3) + 4);
                float4 ua = *(const float4*)(u_f + (i << 3));
                float4 ub = *(const float4*)(u_f + (i << 3) + 4);
                acc = fmaf(__expf(-ta.x), ua.x, acc);
                acc = fmaf(__expf(-ta.y), ua.y, acc);
                acc = fmaf(__expf(-ta.z), ua.z, acc);
                acc = fmaf(__expf(-ta.w), ua.w, acc);
                acc = fmaf(__expf(-tb.x), ub.x, acc);
                acc = fmaf(__expf(-tb.y), ub.y, acc);
                acc = fmaf(__expf(-tb.z), ub.z, acc);
                acc = fmaf(__expf(-tb.w), ub.w, acc);
            }
            acc = fmaxf(acc, 1e-30f);
            c = A[(x << 8) + q] + m + __logf(acc);
        }
    }

    float v = LAl[q] + c;
    float m2 = wred_max(v);
    if ((q & 63) == 0) red[q >> 6] = m2;
    __syncthreads();
    m2 = fmaxf(fmaxf(red[0], red[1]), fmaxf(red[2], red[3]));
    float es = wred_add(__expf(v - m2));
    __syncthreads();
    if ((q & 63) == 0) red[q >> 6] = es;
    __syncthreads();
    if (q == 0) per_seq[b] = m2 + __logf(red[0] + red[1] + red[2] + red[3]);
}

__global__ __launch_bounds__(64) void k_final(const float* per_seq, float* out) {
    if (threadIdx.x == 0) {
        float s = 0.f;
        for (int i = 0; i < BDIM; ++i) s += per_seq[i];
        out[0] = s;
    }
}

extern "C" void kernel_launch(void* const* d_in, const int* in_sizes, int n_in,
                              void* d_out, int out_size, void* d_ws, size_t ws_size,
                              hipStream_t stream) {
    // Map inputs by element count (robust to ordering assumptions).
    const int* xs = nullptr;
    const float *alpha = nullptr, *omega = nullptr, *E = nullptr, *T = nullptr;
    int seen256 = 0;
    for (int i = 0; i < n_in; ++i) {
        int s = in_sizes[i];
        if      (s == 16777216) T  = (const float*)d_in[i];
        else if (s == 65536)    E  = (const float*)d_in[i];
        else if (s == 8192)     xs = (const int*)d_in[i];
        else if (s == 256) { if (seen256++ == 0) alpha = (const float*)d_in[i];
                             else                omega = (const float*)d_in[i]; }
    }

    char* ws = (char*)d_ws;
    float* A       = (float*)(ws + WS_A);
    float* cE      = (float*)(ws + WS_CE);
    float* LOm     = (float*)(ws + WS_LOM);
    float* LAl     = (float*)(ws + WS_LAL);
    float* per_seq = (float*)(ws + WS_PS);
    __half* W      = (__half*)(ws + WS_W);
    int fast = (ws_size >= WS_FAST_BYTES) ? 1 : 0;

    k_erow<<<65, 256, 0, stream>>>(E, omega, alpha, cE, LOm, LAl);
    k_trow<<<16384, 256, 0, stream>>>(T, W, A, fast);
    k_afix<<<256, 256, 0, stream>>>(E, cE, A);
    if (fast) k_main_fast<<<BDIM, 256, 0, stream>>>(xs, W, A, LOm, LAl, per_seq);
    else      k_main_med <<<BDIM, 256, 0, stream>>>(xs, T, A, LOm, LAl, per_seq);
    k_final<<<1, 64, 0, stream>>>(per_seq, (float*)d_out);
}

// Round 6
// 1345.811 us; speedup vs baseline: 1.2219x; 1.2219x over previous
//
#include <hip/hip_runtime.h>
#include <hip/hip_fp16.h>

#define LDIM 512
#define BDIM 16

// ws layout: small arrays first so the fallback path works with small ws.
#define WS_A    0u          // 262144 B  (float A[256*256], A[x*256+q])
#define WS_CE   262144u     // 1024 B
#define WS_LOM  263168u     // 1024 B
#define WS_LAL  264192u     // 1024 B
#define WS_PS   265216u     // 64 B
#define WS_W    270336u     // 33554432 B (fp16 W), 16B aligned
#define WS_FAST_BYTES (270336ull + 33554432ull)

__device__ __forceinline__ float wred_add(float v) {
    #pragma unroll
    for (int off = 32; off; off >>= 1) v += __shfl_xor(v, off);
    return v;
}
__device__ __forceinline__ float wred_max(float v) {
    #pragma unroll
    for (int off = 32; off; off >>= 1) v = fmaxf(v, __shfl_xor(v, off));
    return v;
}

// Michelot exact sparsemax over a wave's 256 values (4 per lane).
// Returns c = <z,p*> - 0.5||p*||^2 + 0.5 (wave-uniform).
__device__ float sparsemax_c4(float z0, float z1, float z2, float z3) {
    float ssum = wred_add(z0 + z1 + z2 + z3);
    float tau = (ssum - 1.0f) * (1.0f / 256.0f);
    int kprev = 256;
    for (int it = 0; it < 64; ++it) {
        float s = 0.f, cnt = 0.f;
        if (z0 > tau) { s += z0; cnt += 1.f; }
        if (z1 > tau) { s += z1; cnt += 1.f; }
        if (z2 > tau) { s += z2; cnt += 1.f; }
        if (z3 > tau) { s += z3; cnt += 1.f; }
        s = wred_add(s);
        cnt = wred_add(cnt);
        tau = (s - 1.0f) / cnt;            // cnt >= 1 invariant (max > tau)
        int k = (int)cnt;
        if (k == kprev) break;
        kprev = k;
    }
    float cs = 0.f, t2 = tau * tau;
    if (z0 > tau) cs += z0 * z0 - t2;
    if (z1 > tau) cs += z1 * z1 - t2;
    if (z2 > tau) cs += z2 * z2 - t2;
    if (z3 > tau) cs += z3 * z3 - t2;
    cs = wred_add(cs);
    return 0.5f * cs + 0.5f;
}

// Rows of E (256) + omega (1) + alpha (1). All float32.
__global__ __launch_bounds__(256) void k_erow(const float* E, const float* omega,
                                              const float* alpha,
                                              float* cE, float* LOm, float* LAl) {
    int wid = blockIdx.x * 4 + (threadIdx.x >> 6);
    if (wid >= 258) return;
    int lane = threadIdx.x & 63;
    const float* row = (wid < 256) ? (E + wid * 256)
                      : (wid == 256 ? omega : alpha);
    float4 z = *(const float4*)(row + lane * 4);
    float c = sparsemax_c4(z.x, z.y, z.z, z.w);
    if (wid < 256) {
        if (lane == 0) cE[wid] = c;
    } else {
        float* dst = (wid == 256) ? LOm : LAl;
        *(float4*)(dst + lane * 4) = make_float4(c - z.x, c - z.y, c - z.z, c - z.w);
    }
}

// wid = x*256+q. A[x*256+q] = c_T(T[q,x,:]); W3[((x*32+i)*256+q)*8+k] = fp16(exp(-T[q,x,8i+k])).
__global__ __launch_bounds__(256) void k_trow(const float* T, __half* W,
                                              float* A, int writeW) {
    int wid = blockIdx.x * 4 + (threadIdx.x >> 6);
    int lane = threadIdx.x & 63;
    int x = wid >> 8, q = wid & 255;
    const float* row = T + ((size_t)((q << 8) | x) << 8);
    float4 z = *(const float4*)(row + lane * 4);
    float c = sparsemax_c4(z.x, z.y, z.z, z.w);
    if (writeW) {
        union { uint2 v; __half h[4]; } wout;
        wout.h[0] = __float2half(__expf(-z.x));
        wout.h[1] = __float2half(__expf(-z.y));
        wout.h[2] = __float2half(__expf(-z.z));
        wout.h[3] = __float2half(__expf(-z.w));
        size_t idx = ((((size_t)x * 32 + (lane >> 1)) * 256 + q) * 8) + (size_t)((lane & 1) * 4);
        *(uint2*)(W + idx) = wout.v;
    }
    if (lane == 0) A[wid] = c;
}

// A[x,q] += cE[q] - E[q,x]
__global__ __launch_bounds__(256) void k_afix(const float* E, const float* cE, float* A) {
    int x = blockIdx.x, q = threadIdx.x;
    A[(x << 8) + q] += cE[q] - E[q * 256 + x];
}

// ---- main recursion: 1024 threads/block, 4-way split dot, prefetched W ----
// tid: q = tid&255, j = tid>>8. Thread (q,j) covers n = j*64 .. j*64+63.
// c[q] lives in registers of the j==0 waves (tid<256).
__global__ __launch_bounds__(1024) void k_main_fast(const int* xs, const __half* W,
                                                    const float* A, const float* LOm,
                                                    const float* LAl, float* per_seq) {
    int b = blockIdx.x, tid = threadIdx.x;
    int q = tid & 255, j = tid >> 8;
    __shared__ int xsh[LDIM];
    __shared__ float red[4];
    __shared__ __align__(16) float u_f[256];
    __shared__ __align__(16) float acc_sh[1024];
    if (tid < LDIM) xsh[tid] = xs[b * LDIM + tid];
    float c = (j == 0) ? LOm[q] : 0.f;
    __syncthreads();

    const __half* Wbase = W + ((size_t)q << 3) + ((size_t)j << 14);
    for (int t = LDIM - 1; t >= 0; --t) {
        int x = xsh[t];
        if (x == 0) continue;                  // block-uniform
        // Issue this step's W loads immediately (depend only on x,q,j);
        // they drain while the reduction/barrier dance below runs.
        const __half* Wp = Wbase + ((size_t)x << 16);
        uint4 wv[8];
        #pragma unroll
        for (int i = 0; i < 8; ++i) wv[i] = *(const uint4*)(Wp + ((size_t)i << 11));
        float Aq = 0.f;
        if (j == 0) {
            Aq = A[(x << 8) + q];              // early issue
            float m0 = wred_max(c);
            if ((tid & 63) == 0) red[tid >> 6] = m0;
        }
        __syncthreads();                       // B1
        float m = fmaxf(fmaxf(red[0], red[1]), fmaxf(red[2], red[3]));
        if (j == 0) u_f[q] = __expf(c - m);
        __syncthreads();                       // B2
        float acc0 = 0.f, acc1 = 0.f;
        const float* up = u_f + (j << 6);
        #pragma unroll
        for (int i = 0; i < 8; i += 2) {
            union { uint4 v; __half h[8]; } w0, w1;
            w0.v = wv[i];
            w1.v = wv[i + 1];
            float4 a0 = *(const float4*)(up + (i << 3));
            float4 b0 = *(const float4*)(up + (i << 3) + 4);
            float4 a1 = *(const float4*)(up + (i << 3) + 8);
            float4 b1 = *(const float4*)(up + (i << 3) + 12);
            acc0 = fmaf(__half2float(w0.h[0]), a0.x, acc0);
            acc1 = fmaf(__half2float(w1.h[0]), a1.x, acc1);
            acc0 = fmaf(__half2float(w0.h[1]), a0.y, acc0);
            acc1 = fmaf(__half2float(w1.h[1]), a1.y, acc1);
            acc0 = fmaf(__half2float(w0.h[2]), a0.z, acc0);
            acc1 = fmaf(__half2float(w1.h[2]), a1.z, acc1);
            acc0 = fmaf(__half2float(w0.h[3]), a0.w, acc0);
            acc1 = fmaf(__half2float(w1.h[3]), a1.w, acc1);
            acc0 = fmaf(__half2float(w0.h[4]), b0.x, acc0);
            acc1 = fmaf(__half2float(w1.h[4]), b1.x, acc1);
            acc0 = fmaf(__half2float(w0.h[5]), b0.y, acc0);
            acc1 = fmaf(__half2float(w1.h[5]), b1.y, acc1);
            acc0 = fmaf(__half2float(w0.h[6]), b0.z, acc0);
            acc1 = fmaf(__half2float(w1.h[6]), b1.z, acc1);
            acc0 = fmaf(__half2float(w0.h[7]), b0.w, acc0);
            acc1 = fmaf(__half2float(w1.h[7]), b1.w, acc1);
        }
        acc_sh[(q << 2) + j] = acc0 + acc1;
        __syncthreads();                       // B3
        if (j == 0) {
            float4 a4 = *(const float4*)(acc_sh + (q << 2));
            float s = (a4.x + a4.y) + (a4.z + a4.w);
            c = Aq + m + __logf(fmaxf(s, 1e-30f));
        }
        // waves j>0 run ahead and prefetch step t-1 while j==0 computes log.
    }

    // per_seq[b] = lse_q(LAl[q] + c[q]); all threads hit the barriers.
    float v = (j == 0) ? (LAl[q] + c) : -3.0e38f;
    float m2 = wred_max(v);
    if (j == 0 && (tid & 63) == 0) red[tid >> 6] = m2;
    __syncthreads();
    m2 = fmaxf(fmaxf(red[0], red[1]), fmaxf(red[2], red[3]));
    float e = (j == 0) ? __expf(v - m2) : 0.f;
    float es = wred_add(e);
    __syncthreads();
    if (j == 0 && (tid & 63) == 0) red[tid >> 6] = es;
    __syncthreads();
    if (tid == 0) per_seq[b] = m2 + __logf(red[0] + red[1] + red[2] + red[3]);
}

// ---- fallback (small ws): read T (f32) directly, exp on the fly ----
__global__ __launch_bounds__(256) void k_main_med(const int* xs, const float* T,
                                                  const float* A, const float* LOm,
                                                  const float* LAl, float* per_seq) {
    int b = blockIdx.x, q = threadIdx.x;
    __shared__ int xsh[LDIM];
    __shared__ float red[4];
    __shared__ __align__(16) float u_f[256];
    for (int i = q; i < LDIM; i += 256) xsh[i] = xs[b * LDIM + i];
    float c = LOm[q];
    __syncthreads();
    for (int t = LDIM - 1; t >= 0; --t) {
        int x = xsh[t];
        if (x != 0) {
            float m = wred_max(c);
            if ((q & 63) == 0) red[q >> 6] = m;
            __syncthreads();
            m = fmaxf(fmaxf(red[0], red[1]), fmaxf(red[2], red[3]));
            u_f[q] = __expf(c - m);
            __syncthreads();
            const float* Tp = T + (((size_t)(q << 8) + (size_t)x) << 8);
            float acc = 0.f;
            #pragma unroll 4
            for (int i = 0; i < 32; ++i) {
                float4 ta = *(const float4*)(Tp + (i << 3));
                float4 tb = *(const float4*)(Tp + (i << 3) + 4);
                float4 ua = *(const float4*)(u_f + (i << 3));
                float4 ub = *(const float4*)(u_f + (i << 3) + 4);
                acc = fmaf(__expf(-ta.x), ua.x, acc);
                acc = fmaf(__expf(-ta.y), ua.y, acc);
                acc = fmaf(__expf(-ta.z), ua.z, acc);
                acc = fmaf(__expf(-ta.w), ua.w, acc);
                acc = fmaf(__expf(-tb.x), ub.x, acc);
                acc = fmaf(__expf(-tb.y), ub.y, acc);
                acc = fmaf(__expf(-tb.z), ub.z, acc);
                acc = fmaf(__expf(-tb.w), ub.w, acc);
            }
            acc = fmaxf(acc, 1e-30f);
            c = A[(x << 8) + q] + m + __logf(acc);
        }
    }
    float v = LAl[q] + c;
    float m2 = wred_max(v);
    if ((q & 63) == 0) red[q >> 6] = m2;
    __syncthreads();
    m2 = fmaxf(fmaxf(red[0], red[1]), fmaxf(red[2], red[3]));
    float es = wred_add(__expf(v - m2));
    __syncthreads();
    if ((q & 63) == 0) red[q >> 6] = es;
    __syncthreads();
    if (q == 0) per_seq[b] = m2 + __logf(red[0] + red[1] + red[2] + red[3]);
}

__global__ __launch_bounds__(64) void k_final(const float* per_seq, float* out) {
    if (threadIdx.x == 0) {
        float s = 0.f;
        for (int i = 0; i < BDIM; ++i) s += per_seq[i];
        out[0] = s;
    }
}

extern "C" void kernel_launch(void* const* d_in, const int* in_sizes, int n_in,
                              void* d_out, int out_size, void* d_ws, size_t ws_size,
                              hipStream_t stream) {
    const int* xs = nullptr;
    const float *alpha = nullptr, *omega = nullptr, *E = nullptr, *T = nullptr;
    int seen256 = 0;
    for (int i = 0; i < n_in; ++i) {
        int s = in_sizes[i];
        if      (s == 16777216) T  = (const float*)d_in[i];
        else if (s == 65536)    E  = (const float*)d_in[i];
        else if (s == 8192)     xs = (const int*)d_in[i];
        else if (s == 256) { if (seen256++ == 0) alpha = (const float*)d_in[i];
                             else                omega = (const float*)d_in[i]; }
    }

    char* ws = (char*)d_ws;
    float* A       = (float*)(ws + WS_A);
    float* cE      = (float*)(ws + WS_CE);
    float* LOm     = (float*)(ws + WS_LOM);
    float* LAl     = (float*)(ws + WS_LAL);
    float* per_seq = (float*)(ws + WS_PS);
    __half* W      = (__half*)(ws + WS_W);
    int fast = (ws_size >= WS_FAST_BYTES) ? 1 : 0;

    k_erow<<<65, 256, 0, stream>>>(E, omega, alpha, cE, LOm, LAl);
    k_trow<<<16384, 256, 0, stream>>>(T, W, A, fast);
    k_afix<<<256, 256, 0, stream>>>(E, cE, A);
    if (fast) k_main_fast<<<BDIM, 1024, 0, stream>>>(xs, W, A, LOm, LAl, per_seq);
    else      k_main_med <<<BDIM, 256, 0, stream>>>(xs, T, A, LOm, LAl, per_seq);
    k_final<<<1, 64, 0, stream>>>(per_seq, (float*)d_out);
}

// Round 7
// 850.720 us; speedup vs baseline: 1.9331x; 1.5820x over previous
//
#include <hip/hip_runtime.h>
#include <hip/hip_fp16.h>

#define LDIM 512
#define BDIM 16

// ws layout: small arrays first so the fallback path works with small ws.
#define WS_A    0u          // 262144 B  (float A[256*256], A[x*256+q])
#define WS_CE   262144u     // 1024 B
#define WS_LOM  263168u     // 1024 B
#define WS_LAL  264192u     // 1024 B
#define WS_PS   265216u     // 64 B
#define WS_W    270336u     // 16777216 B (fp8 W), 16B aligned
#define WS_FAST_BYTES (270336ull + 16777216ull)

typedef float f32x2 __attribute__((ext_vector_type(2)));

__device__ __forceinline__ float wred_add(float v) {
    #pragma unroll
    for (int off = 32; off; off >>= 1) v += __shfl_xor(v, off);
    return v;
}
__device__ __forceinline__ float wred_max(float v) {
    #pragma unroll
    for (int off = 32; off; off >>= 1) v = fmaxf(v, __shfl_xor(v, off));
    return v;
}

#if __has_builtin(__builtin_amdgcn_cvt_pk_f32_fp8) && __has_builtin(__builtin_amdgcn_cvt_pk_fp8_f32)
#define HW_FP8 1
#else
#define HW_FP8 0
#endif

// Fallback software e4m3fn (normals only — our W ∈ [0.5, 2)).
__device__ __forceinline__ unsigned int sw_fp8_enc(float a) {
    union { float f; unsigned int u; } x; x.f = a;
    unsigned int u = x.u + 0x80000u;               // round at mantissa bit 19
    return (((u >> 23) & 0xffu) - 120u) * 8u + ((u >> 20) & 7u);
}
__device__ __forceinline__ float sw_fp8_dec(unsigned int b) {
    union { unsigned int u; float f; } x;
    x.u = ((b & 0x7fu) << 20) + (120u << 23);
    return x.f;
}
__device__ __forceinline__ unsigned int pack4_fp8(float a, float b, float c, float d) {
#if HW_FP8
    int v = 0;
    v = __builtin_amdgcn_cvt_pk_fp8_f32(a, b, v, false);   // bytes 0,1
    v = __builtin_amdgcn_cvt_pk_fp8_f32(c, d, v, true);    // bytes 2,3
    return (unsigned int)v;
#else
    return sw_fp8_enc(a) | (sw_fp8_enc(b) << 8) | (sw_fp8_enc(c) << 16) | (sw_fp8_enc(d) << 24);
#endif
}

// Michelot exact sparsemax over a wave's 256 values (4 per lane).
// Returns c = <z,p*> - 0.5||p*||^2 + 0.5 (wave-uniform).
__device__ float sparsemax_c4(float z0, float z1, float z2, float z3) {
    float ssum = wred_add(z0 + z1 + z2 + z3);
    float tau = (ssum - 1.0f) * (1.0f / 256.0f);
    int kprev = 256;
    for (int it = 0; it < 64; ++it) {
        float s = 0.f, cnt = 0.f;
        if (z0 > tau) { s += z0; cnt += 1.f; }
        if (z1 > tau) { s += z1; cnt += 1.f; }
        if (z2 > tau) { s += z2; cnt += 1.f; }
        if (z3 > tau) { s += z3; cnt += 1.f; }
        s = wred_add(s);
        cnt = wred_add(cnt);
        tau = (s - 1.0f) / cnt;            // cnt >= 1 invariant (max > tau)
        int k = (int)cnt;
        if (k == kprev) break;
        kprev = k;
    }
    float cs = 0.f, t2 = tau * tau;
    if (z0 > tau) cs += z0 * z0 - t2;
    if (z1 > tau) cs += z1 * z1 - t2;
    if (z2 > tau) cs += z2 * z2 - t2;
    if (z3 > tau) cs += z3 * z3 - t2;
    cs = wred_add(cs);
    return 0.5f * cs + 0.5f;
}

// Rows of E (256) + omega (1) + alpha (1). All float32.
__global__ __launch_bounds__(256) void k_erow(const float* E, const float* omega,
                                              const float* alpha,
                                              float* cE, float* LOm, float* LAl) {
    int wid = blockIdx.x * 4 + (threadIdx.x >> 6);
    if (wid >= 258) return;
    int lane = threadIdx.x & 63;
    const float* row = (wid < 256) ? (E + wid * 256)
                      : (wid == 256 ? omega : alpha);
    float4 z = *(const float4*)(row + lane * 4);
    float c = sparsemax_c4(z.x, z.y, z.z, z.w);
    if (wid < 256) {
        if (lane == 0) cE[wid] = c;
    } else {
        float* dst = (wid == 256) ? LOm : LAl;
        *(float4*)(dst + lane * 4) = make_float4(c - z.x, c - z.y, c - z.z, c - z.w);
    }
}

// wid = x*256+q. A[x*256+q] = c_T(T[q,x,:]).
// W8 layout: byte ((x*16 + d)*256 + q)*16 + e  holds fp8(exp(-T[q,x, n=d*16+e])).
__global__ __launch_bounds__(256) void k_trow(const float* T, unsigned char* W8,
                                              float* A, int writeW) {
    int wid = blockIdx.x * 4 + (threadIdx.x >> 6);
    int lane = threadIdx.x & 63;
    int x = wid >> 8, q = wid & 255;
    const float* row = T + ((size_t)((q << 8) | x) << 8);
    float4 z = *(const float4*)(row + lane * 4);
    float c = sparsemax_c4(z.x, z.y, z.z, z.w);
    if (writeW) {
        unsigned int packed = pack4_fp8(__expf(-z.x), __expf(-z.y),
                                        __expf(-z.z), __expf(-z.w));
        // lane covers n = lane*4 .. lane*4+3  ->  d = lane>>2, e0 = (lane&3)*4
        size_t off = (((size_t)(x * 16 + (lane >> 2)) * 256 + q) << 4) + (size_t)((lane & 3) * 4);
        *(unsigned int*)(W8 + off) = packed;
    }
    if (lane == 0) A[wid] = c;
}

// A[x,q] += cE[q] - E[q,x]
__global__ __launch_bounds__(256) void k_afix(const float* E, const float* cE, float* A) {
    int x = blockIdx.x, q = threadIdx.x;
    A[(x << 8) + q] += cE[q] - E[q * 256 + x];
}

// ---- main recursion: 1024 threads/block, 4-way split dot, fp8 W ----
// tid: q = tid&255, j = tid>>8. Thread (q,j) covers n = j*64 .. j*64+63.
__global__ __launch_bounds__(1024) void k_main_fast(const int* xs, const unsigned char* W8,
                                                    const float* A, const float* LOm,
                                                    const float* LAl, float* per_seq) {
    int b = blockIdx.x, tid = threadIdx.x;
    int q = tid & 255, j = tid >> 8;
    __shared__ int xsh[LDIM];
    __shared__ float red[4];
    __shared__ __align__(16) float u_f[256];
    __shared__ __align__(16) float acc_sh[1024];
    if (tid < LDIM) xsh[tid] = xs[b * LDIM + tid];
    float c = (j == 0) ? LOm[q] : 0.f;
    __syncthreads();

    // thread's W base: x*65536 + (j*4)*4096 + q*16
    const unsigned char* Wbase = W8 + ((size_t)q << 4) + ((size_t)j << 14);
    for (int t = LDIM - 1; t >= 0; --t) {
        int x = xsh[t];
        if (x == 0) continue;                  // block-uniform
        const unsigned char* Wp = Wbase + ((size_t)x << 16);
        uint4 wv[4];
        #pragma unroll
        for (int i = 0; i < 4; ++i) wv[i] = *(const uint4*)(Wp + ((size_t)i << 12));
        float Aq = 0.f;
        if (j == 0) {
            Aq = A[(x << 8) + q];              // early issue
            float m0 = wred_max(c);
            if ((tid & 63) == 0) red[tid >> 6] = m0;
        }
        __syncthreads();                       // B1
        float m = fmaxf(fmaxf(red[0], red[1]), fmaxf(red[2], red[3]));
        if (j == 0) u_f[q] = __expf(c - m);
        __syncthreads();                       // B2
        float acc0 = 0.f, acc1 = 0.f;
        const float* up = u_f + (j << 6);
        #pragma unroll
        for (int i = 0; i < 4; ++i) {
            uint4 w = wv[i];
            float4 ua = *(const float4*)(up + (i << 4) + 0);
            float4 ub = *(const float4*)(up + (i << 4) + 4);
            float4 uc = *(const float4*)(up + (i << 4) + 8);
            float4 ud = *(const float4*)(up + (i << 4) + 12);
#if HW_FP8
            f32x2 p0 = __builtin_amdgcn_cvt_pk_f32_fp8((int)w.x, false);
            f32x2 p1 = __builtin_amdgcn_cvt_pk_f32_fp8((int)w.x, true);
            f32x2 p2 = __builtin_amdgcn_cvt_pk_f32_fp8((int)w.y, false);
            f32x2 p3 = __builtin_amdgcn_cvt_pk_f32_fp8((int)w.y, true);
            f32x2 p4 = __builtin_amdgcn_cvt_pk_f32_fp8((int)w.z, false);
            f32x2 p5 = __builtin_amdgcn_cvt_pk_f32_fp8((int)w.z, true);
            f32x2 p6 = __builtin_amdgcn_cvt_pk_f32_fp8((int)w.w, false);
            f32x2 p7 = __builtin_amdgcn_cvt_pk_f32_fp8((int)w.w, true);
#else
            f32x2 p0 = { sw_fp8_dec(w.x & 255u), sw_fp8_dec((w.x >> 8) & 255u) };
            f32x2 p1 = { sw_fp8_dec((w.x >> 16) & 255u), sw_fp8_dec(w.x >> 24) };
            f32x2 p2 = { sw_fp8_dec(w.y & 255u), sw_fp8_dec((w.y >> 8) & 255u) };
            f32x2 p3 = { sw_fp8_dec((w.y >> 16) & 255u), sw_fp8_dec(w.y >> 24) };
            f32x2 p4 = { sw_fp8_dec(w.z & 255u), sw_fp8_dec((w.z >> 8) & 255u) };
            f32x2 p5 = { sw_fp8_dec((w.z >> 16) & 255u), sw_fp8_dec(w.z >> 24) };
            f32x2 p6 = { sw_fp8_dec(w.w & 255u), sw_fp8_dec((w.w >> 8) & 255u) };
            f32x2 p7 = { sw_fp8_dec((w.w >> 16) & 255u), sw_fp8_dec(w.w >> 24) };
#endif
            acc0 = fmaf(p0.x, ua.x, acc0); acc1 = fmaf(p0.y, ua.y, acc1);
            acc0 = fmaf(p1.x, ua.z, acc0); acc1 = fmaf(p1.y, ua.w, acc1);
            acc0 = fmaf(p2.x, ub.x, acc0); acc1 = fmaf(p2.y, ub.y, acc1);
            acc0 = fmaf(p3.x, ub.z, acc0); acc1 = fmaf(p3.y, ub.w, acc1);
            acc0 = fmaf(p4.x, uc.x, acc0); acc1 = fmaf(p4.y, uc.y, acc1);
            acc0 = fmaf(p5.x, uc.z, acc0); acc1 = fmaf(p5.y, uc.w, acc1);
            acc0 = fmaf(p6.x, ud.x, acc0); acc1 = fmaf(p6.y, ud.y, acc1);
            acc0 = fmaf(p7.x, ud.z, acc0); acc1 = fmaf(p7.y, ud.w, acc1);
        }
        acc_sh[(j << 8) + q] = acc0 + acc1;    // conflict-free: lanes stride-1
        __syncthreads();                       // B3
        if (j == 0) {
            float s = (acc_sh[q] + acc_sh[256 + q]) + (acc_sh[512 + q] + acc_sh[768 + q]);
            c = Aq + m + __logf(fmaxf(s, 1e-30f));
        }
    }

    // per_seq[b] = lse_q(LAl[q] + c[q]); all threads hit the barriers.
    float v = (j == 0) ? (LAl[q] + c) : -3.0e38f;
    float m2 = wred_max(v);
    if (j == 0 && (tid & 63) == 0) red[tid >> 6] = m2;
    __syncthreads();
    m2 = fmaxf(fmaxf(red[0], red[1]), fmaxf(red[2], red[3]));
    float e = (j == 0) ? __expf(v - m2) : 0.f;
    float es = wred_add(e);
    __syncthreads();
    if (j == 0 && (tid & 63) == 0) red[tid >> 6] = es;
    __syncthreads();
    if (tid == 0) per_seq[b] = m2 + __logf(red[0] + red[1] + red[2] + red[3]);
}

// ---- fallback (small ws): read T (f32) directly, exp on the fly ----
__global__ __launch_bounds__(256) void k_main_med(const int* xs, const float* T,
                                                  const float* A, const float* LOm,
                                                  const float* LAl, float* per_seq) {
    int b = blockIdx.x, q = threadIdx.x;
    __shared__ int xsh[LDIM];
    __shared__ float red[4];
    __shared__ __align__(16) float u_f[256];
    for (int i = q; i < LDIM; i += 256) xsh[i] = xs[b * LDIM + i];
    float c = LOm[q];
    __syncthreads();
    for (int t = LDIM - 1; t >= 0; --t) {
        int x = xsh[t];
        if (x != 0) {
            float m = wred_max(c);
            if ((q & 63) == 0) red[q >> 6] = m;
            __syncthreads();
            m = fmaxf(fmaxf(red[0], red[1]), fmaxf(red[2], red[3]));
            u_f[q] = __expf(c - m);
            __syncthreads();
            const float* Tp = T + (((size_t)(q << 8) + (size_t)x) << 8);
            float acc = 0.f;
            #pragma unroll 4
            for (int i = 0; i < 32; ++i) {
                float4 ta = *(const float4*)(Tp + (i << 3));
                float4 tb = *(const float4*)(Tp + (i << 3) + 4);
                float4 ua = *(const float4*)(u_f + (i << 3));
                float4 ub = *(const float4*)(u_f + (i << 3) + 4);
                acc = fmaf(__expf(-ta.x), ua.x, acc);
                acc = fmaf(__expf(-ta.y), ua.y, acc);
                acc = fmaf(__expf(-ta.z), ua.z, acc);
                acc = fmaf(__expf(-ta.w), ua.w, acc);
                acc = fmaf(__expf(-tb.x), ub.x, acc);
                acc = fmaf(__expf(-tb.y), ub.y, acc);
                acc = fmaf(__expf(-tb.z), ub.z, acc);
                acc = fmaf(__expf(-tb.w), ub.w, acc);
            }
            acc = fmaxf(acc, 1e-30f);
            c = A[(x << 8) + q] + m + __logf(acc);
        }
    }
    float v = LAl[q] + c;
    float m2 = wred_max(v);
    if ((q & 63) == 0) red[q >> 6] = m2;
    __syncthreads();
    m2 = fmaxf(fmaxf(red[0], red[1]), fmaxf(red[2], red[3]));
    float es = wred_add(__expf(v - m2));
    __syncthreads();
    if ((q & 63) == 0) red[q >> 6] = es;
    __syncthreads();
    if (q == 0) per_seq[b] = m2 + __logf(red[0] + red[1] + red[2] + red[3]);
}

__global__ __launch_bounds__(64) void k_final(const float* per_seq, float* out) {
    if (threadIdx.x == 0) {
        float s = 0.f;
        for (int i = 0; i < BDIM; ++i) s += per_seq[i];
        out[0] = s;
    }
}

extern "C" void kernel_launch(void* const* d_in, const int* in_sizes, int n_in,
                              void* d_out, int out_size, void* d_ws, size_t ws_size,
                              hipStream_t stream) {
    const int* xs = nullptr;
    const float *alpha = nullptr, *omega = nullptr, *E = nullptr, *T = nullptr;
    int seen256 = 0;
    for (int i = 0; i < n_in; ++i) {
        int s = in_sizes[i];
        if      (s == 16777216) T  = (const float*)d_in[i];
        else if (s == 65536)    E  = (const float*)d_in[i];
        else if (s == 8192)     xs = (const int*)d_in[i];
        else if (s == 256) { if (seen256++ == 0) alpha = (const float*)d_in[i];
                             else                omega = (const float*)d_in[i]; }
    }

    char* ws = (char*)d_ws;
    float* A        = (float*)(ws + WS_A);
    float* cE       = (float*)(ws + WS_CE);
    float* LOm      = (float*)(ws + WS_LOM);
    float* LAl      = (float*)(ws + WS_LAL);
    float* per_seq  = (float*)(ws + WS_PS);
    unsigned char* W8 = (unsigned char*)(ws + WS_W);
    int fast = (ws_size >= WS_FAST_BYTES) ? 1 : 0;

    k_erow<<<65, 256, 0, stream>>>(E, omega, alpha, cE, LOm, LAl);
    k_trow<<<16384, 256, 0, stream>>>(T, W8, A, fast);
    k_afix<<<256, 256, 0, stream>>>(E, cE, A);
    if (fast) k_main_fast<<<BDIM, 1024, 0, stream>>>(xs, W8, A, LOm, LAl, per_seq);
    else      k_main_med <<<BDIM, 256, 0, stream>>>(xs, T, A, LOm, LAl, per_seq);
    k_final<<<1, 64, 0, stream>>>(per_seq, (float*)d_out);
}